// Round 8
// baseline (377.785 us; speedup 1.0000x reference)
//
#include <hip/hip_runtime.h>

#define HIDDEN 2048
#define NB 64
#define NT 512
#define NK 49

typedef __attribute__((ext_vector_type(4))) float f32x4;
typedef __attribute__((ext_vector_type(8))) short short8;

__device__ __forceinline__ unsigned cvtpk_bf16(float a, float b) {
    unsigned r;
    asm("v_cvt_pk_bf16_f32 %0, %1, %2" : "=v"(r) : "v"(a), "v"(b));
    return r;
}

// scalar RNE f32->bf16 (convert kernel only; not perf-critical)
__device__ __forceinline__ unsigned short f2bf(float x) {
    union { float f; unsigned u; } v; v.f = x;
    unsigned r = v.u + 0x7FFF + ((v.u >> 16) & 1);
    return (unsigned short)(r >> 16);
}

// ---------------------------------------------------------------------------
// Kernel 0 v2: convert + swizzle W{g,s,v} (fp32 [49][2048]) into MFMA
// B-fragment order, K-chunk-contiguous (unchanged, proven):
//   index tau = ((m*64 + st)*4 + c)*64 + lane   (8 bf16 = 16B per entry)
// ---------------------------------------------------------------------------
__global__ __launch_bounds__(256) void convert_w(
    const float* __restrict__ Wg, const float* __restrict__ Ws,
    const float* __restrict__ Wv, unsigned short* __restrict__ Wf)
{
    int tau = blockIdx.x * 256 + threadIdx.x;      // 0..49151
    int m   = tau >> 14;
    int rem = tau & 16383;
    int st  = rem >> 8;
    int c   = (rem >> 6) & 3;
    int l   = rem & 63;
    int col = c * 16 + (l & 15);
    int k0  = st * 32 + ((l >> 4) << 3);

    const float* W = (m == 0) ? Wg : (m == 1) ? Ws : Wv;
    unsigned short out[8];
    if (col < NK) {
        const float* p = W + (size_t)col * HIDDEN + k0;
        #pragma unroll
        for (int j = 0; j < 8; j++) out[j] = f2bf(p[j]);
    } else {
        #pragma unroll
        for (int j = 0; j < 8; j++) out[j] = 0;
    }
    unsigned short* dst = Wf + (size_t)tau * 8;
    #pragma unroll
    for (int j = 0; j < 8; j++) dst[j] = out[j];
}

// ---------------------------------------------------------------------------
// Kernel 1 v6: barrier-free, LDS-free streaming MFMA GEMM with manual
// vmcnt accounting. One wave = 16 rows x 64 cols, fully independent.
// 3-deep slot rotation, 6 asm loads/iter (2 A HBM + 4 B L2), always 18
// loads in flight; consume gated by s_waitcnt vmcnt(12)+sched_barrier(0).
// Tail: clamped re-issues of iter 63 keep the count uniform.
// ---------------------------------------------------------------------------
#define ISSUE6(Aa, Ab, B0, B1, B2, B3, g) { \
    int gc_ = (g) < 64 ? (g) : 63; \
    const float*  _pa = ap + (size_t)gc_ * 32; \
    const short8* _pb = bp + (size_t)gc_ * 256; \
    asm volatile("global_load_dwordx4 %0, %1, off"             : "=&v"(Aa) : "v"(_pa)); \
    asm volatile("global_load_dwordx4 %0, %1, off offset:16"   : "=&v"(Ab) : "v"(_pa)); \
    asm volatile("global_load_dwordx4 %0, %1, off"             : "=&v"(B0) : "v"(_pb)); \
    asm volatile("global_load_dwordx4 %0, %1, off offset:1024" : "=&v"(B1) : "v"(_pb)); \
    asm volatile("global_load_dwordx4 %0, %1, off offset:2048" : "=&v"(B2) : "v"(_pb)); \
    asm volatile("global_load_dwordx4 %0, %1, off offset:3072" : "=&v"(B3) : "v"(_pb)); }

#define CONSUME(Aa, Ab, B0, B1, B2, B3) { \
    asm volatile("s_waitcnt vmcnt(12)" ::: "memory"); \
    __builtin_amdgcn_sched_barrier(0); \
    union { short8 v; unsigned u[4]; } a_; \
    a_.u[0] = cvtpk_bf16(Aa[0], Aa[1]); \
    a_.u[1] = cvtpk_bf16(Aa[2], Aa[3]); \
    a_.u[2] = cvtpk_bf16(Ab[0], Ab[1]); \
    a_.u[3] = cvtpk_bf16(Ab[2], Ab[3]); \
    acc0 = __builtin_amdgcn_mfma_f32_16x16x32_bf16(a_.v, B0, acc0, 0, 0, 0); \
    acc1 = __builtin_amdgcn_mfma_f32_16x16x32_bf16(a_.v, B1, acc1, 0, 0, 0); \
    acc2 = __builtin_amdgcn_mfma_f32_16x16x32_bf16(a_.v, B2, acc2, 0, 0, 0); \
    acc3 = __builtin_amdgcn_mfma_f32_16x16x32_bf16(a_.v, B3, acc3, 0, 0, 0); }

__global__ __launch_bounds__(256) void gemm_mfma(
    const float* __restrict__ h, const float* __restrict__ s,
    const float* __restrict__ V, const unsigned short* __restrict__ Wf,
    float* __restrict__ pg, float* __restrict__ ps, float* __restrict__ pv)
{
    int w = threadIdx.x >> 6, lane = threadIdx.x & 63;
    int gw = blockIdx.x * 4 + w;

    const float* A; float* C; int rowBase; const unsigned short* wfm;
    if (gw < 2048)      { A = h; C = pg; rowBase = gw * 16;          wfm = Wf; }
    else if (gw < 4096) { A = s; C = ps; rowBase = (gw - 2048) * 16; wfm = Wf + (size_t)16384 * 8; }
    else                { A = V; C = pv; rowBase = (gw - 4096) * 16; wfm = Wf + (size_t)32768 * 8; }

    const float* ap = A + (size_t)(rowBase + (lane & 15)) * HIDDEN + ((lane >> 4) << 3);
    const short8* bp = (const short8*)wfm + lane;   // (st,c) at + (st*4+c)*64

    f32x4 acc0 = {0.f, 0.f, 0.f, 0.f};
    f32x4 acc1 = acc0, acc2 = acc0, acc3 = acc0;

    // 3 slots of named SSA values
    f32x4 A0a, A0b, A1a, A1b, A2a, A2b;
    short8 B00, B01, B02, B03, B10, B11, B12, B13, B20, B21, B22, B23;

    ISSUE6(A0a, A0b, B00, B01, B02, B03, 0)
    ISSUE6(A1a, A1b, B10, B11, B12, B13, 1)
    ISSUE6(A2a, A2b, B20, B21, B22, B23, 2)

    #pragma unroll 1
    for (int g = 0; g < 63; g += 3) {
        CONSUME(A0a, A0b, B00, B01, B02, B03)
        ISSUE6 (A0a, A0b, B00, B01, B02, B03, g + 3)
        CONSUME(A1a, A1b, B10, B11, B12, B13)
        ISSUE6 (A1a, A1b, B10, B11, B12, B13, g + 4)
        CONSUME(A2a, A2b, B20, B21, B22, B23)
        ISSUE6 (A2a, A2b, B20, B21, B22, B23, g + 5)
    }
    // iter 63 (slot 0)
    CONSUME(A0a, A0b, B00, B01, B02, B03)

    // drain clamp re-issues before stores/endpgm
    asm volatile("s_waitcnt vmcnt(0)" ::: "memory");
    __builtin_amdgcn_sched_barrier(0);

    // C/D layout (verified m89): col = lane&15, row = (lane>>4)*4 + reg
    int colb  = lane & 15;
    int rquad = (lane >> 4) << 2;
    float* crow = C + (size_t)(rowBase + rquad) * NK + colb;
    #pragma unroll
    for (int r = 0; r < 4; r++) {
        crow[(size_t)r * NK + 0]  = acc0[r];
        crow[(size_t)r * NK + 16] = acc1[r];
        crow[(size_t)r * NK + 32] = acc2[r];
    }
    if (colb == 0) {
        #pragma unroll
        for (int r = 0; r < 4; r++) crow[(size_t)r * NK + 48] = acc3[r];
    }
}

// fast tanh: 1 - 2/(exp(2x)+1); safe at +-inf of exp
__device__ __forceinline__ float ftanh(float x) {
    float e = __expf(2.f * x);
    return 1.f - 2.f * __builtin_amdgcn_rcpf(e + 1.f);
}

// ---------------------------------------------------------------------------
// Kernel 2: per-(b,t) scores + softmaxes. One wave per row (b,t). (unchanged)
// ---------------------------------------------------------------------------
__global__ __launch_bounds__(256) void zab_kernel(
    const float* __restrict__ pg, const float* __restrict__ ps,
    const float* __restrict__ pv, const float* __restrict__ Wh,
    float* __restrict__ alpha, float* __restrict__ beta)
{
    int w = threadIdx.x >> 6, lane = threadIdx.x & 63;
    int row = blockIdx.x * 4 + w;        // 0..32767
    int b = row >> 9;

    const float* pgrow = pg + (size_t)row * NK;
    const float* psrow = ps + (size_t)row * NK;

    // phase A: z_ext
    float va = 0.f;
    if (lane < NK)
        va = ftanh(psrow[lane] + pgrow[lane]) * Wh[lane];
    float z_ext = va;
    #pragma unroll
    for (int off = 32; off; off >>= 1) z_ext += __shfl_xor(z_ext, off);

    // phase B: z[k]
    float z = -1e30f;
    if (lane < NK) {
        const float* pvrow = pv + ((size_t)b * NK + lane) * NK;
        float acc = 0.f;
        for (int j = 0; j < NK; j++)
            acc = fmaf(ftanh(pvrow[j] + pgrow[j]), Wh[j], acc);
        z = acc;
    }

    // softmax over k (49)
    float m = z;
    #pragma unroll
    for (int off = 32; off; off >>= 1) m = fmaxf(m, __shfl_xor(m, off));
    float p = (lane < NK) ? __expf(z - m) : 0.f;
    float ssum = p;
    #pragma unroll
    for (int off = 32; off; off >>= 1) ssum += __shfl_xor(ssum, off);
    float a = p * __builtin_amdgcn_rcpf(ssum);

    if (lane < NK)
        alpha[(size_t)row * NK + lane] = a;

    // extended softmax -> beta
    float me = fmaxf(m, z_ext);
    float se = ssum * __expf(m - me) + __expf(z_ext - me);
    float bet = __expf(z_ext - me) * __builtin_amdgcn_rcpf(se);
    if (lane == 0) beta[row] = bet;
}

// ---------------------------------------------------------------------------
// Kernel 3: c_hat = beta*sent + (1-beta)*(alpha @ V). (unchanged)
// ---------------------------------------------------------------------------
__global__ __launch_bounds__(256) void chat_kernel(
    const float* __restrict__ V, const float* __restrict__ sent,
    const float* __restrict__ alpha, const float* __restrict__ beta,
    float* __restrict__ chat)
{
    int d0 = blockIdx.x * 128;
    int t0 = blockIdx.y * 32;
    int b  = blockIdx.z;

    __shared__ float alpha_s[NK][36];   // transposed: [k][t], stride 36
    __shared__ float beta_s[32];

    int tid = threadIdx.x;

    const float* arow = alpha + ((size_t)b * NT + t0) * NK;  // 1568 contiguous
    for (int i = tid; i < 32 * NK; i += 256) {
        int t = i / NK, k = i - t * NK;
        alpha_s[k][t] = arow[i];
    }
    if (tid < 32) beta_s[tid] = beta[(size_t)b * NT + t0 + tid];
    __syncthreads();

    int tx = tid & 31;          // d-group: d = d0 + tx*4
    int ty = tid >> 5;          // t-group: t = t0 + ty*4 + i

    const float* vp = V + (size_t)b * NK * HIDDEN + d0 + tx * 4;

    float4 acc[4];
    #pragma unroll
    for (int i = 0; i < 4; i++) acc[i] = make_float4(0.f, 0.f, 0.f, 0.f);

    #pragma unroll 7
    for (int k = 0; k < NK; k++) {
        float4 vv = *(const float4*)(vp + (size_t)k * HIDDEN);
        float4 a4 = *(const float4*)&alpha_s[k][ty * 4];
        acc[0].x = fmaf(a4.x, vv.x, acc[0].x);
        acc[0].y = fmaf(a4.x, vv.y, acc[0].y);
        acc[0].z = fmaf(a4.x, vv.z, acc[0].z);
        acc[0].w = fmaf(a4.x, vv.w, acc[0].w);
        acc[1].x = fmaf(a4.y, vv.x, acc[1].x);
        acc[1].y = fmaf(a4.y, vv.y, acc[1].y);
        acc[1].z = fmaf(a4.y, vv.z, acc[1].z);
        acc[1].w = fmaf(a4.y, vv.w, acc[1].w);
        acc[2].x = fmaf(a4.z, vv.x, acc[2].x);
        acc[2].y = fmaf(a4.z, vv.y, acc[2].y);
        acc[2].z = fmaf(a4.z, vv.z, acc[2].z);
        acc[2].w = fmaf(a4.z, vv.w, acc[2].w);
        acc[3].x = fmaf(a4.w, vv.x, acc[3].x);
        acc[3].y = fmaf(a4.w, vv.y, acc[3].y);
        acc[3].z = fmaf(a4.w, vv.z, acc[3].z);
        acc[3].w = fmaf(a4.w, vv.w, acc[3].w);
    }

    #pragma unroll
    for (int i = 0; i < 4; i++) {
        int t = ty * 4 + i;
        float bt = beta_s[t];
        const float* sp = sent + ((size_t)b * NT + t0 + t) * HIDDEN + d0 + tx * 4;
        float*       op = chat + ((size_t)b * NT + t0 + t) * HIDDEN + d0 + tx * 4;
        float4 sv = *(const float4*)sp;
        float4 o;
        o.x = fmaf(bt, sv.x, (1.f - bt) * acc[i].x);
        o.y = fmaf(bt, sv.y, (1.f - bt) * acc[i].y);
        o.z = fmaf(bt, sv.z, (1.f - bt) * acc[i].z);
        o.w = fmaf(bt, sv.w, (1.f - bt) * acc[i].w);
        *(float4*)op = o;
    }
}

extern "C" void kernel_launch(void* const* d_in, const int* in_sizes, int n_in,
                              void* d_out, int out_size, void* d_ws, size_t ws_size,
                              hipStream_t stream)
{
    const float* V    = (const float*)d_in[0];
    const float* h_t  = (const float*)d_in[1];
    const float* sent = (const float*)d_in[2];
    const float* Wv   = (const float*)d_in[3];
    const float* Wg   = (const float*)d_in[4];
    const float* Ws   = (const float*)d_in[5];
    const float* Wh   = (const float*)d_in[6];

    float* out   = (float*)d_out;
    float* chat  = out;                                   // B*T*HIDDEN
    float* alpha = out + (size_t)NB * NT * HIDDEN;        // B*T*K
    float* beta  = alpha + (size_t)NB * NT * NK;          // B*T

    float* ws = (float*)d_ws;
    float* pg = ws;                                       // 32768*49
    float* ps = pg + (size_t)NB * NT * NK;                // 32768*49
    float* pv = ps + (size_t)NB * NT * NK;                // 3136*49
    unsigned short* Wf = (unsigned short*)(pv + (size_t)NB * NK * NK); // 3*16384*8 bf16

    convert_w<<<192, 256, 0, stream>>>(Wg, Ws, Wv, Wf);
    gemm_mfma<<<1073, 256, 0, stream>>>(h_t, sent, V, Wf, pg, ps, pv);
    zab_kernel<<<(NB * NT) / 4, 256, 0, stream>>>(pg, ps, pv, Wh, alpha, beta);
    chat_kernel<<<dim3(HIDDEN / 128, NT / 32, NB), 256, 0, stream>>>(V, sent, alpha, beta, chat);
}

// Round 9
// 358.324 us; speedup vs baseline: 1.0543x; 1.0543x over previous
//
#include <hip/hip_runtime.h>

#define HIDDEN 2048
#define NB 64
#define NT 512
#define NK 49

#define BM 128          // rows per block (8 waves x 16)
#define BK 64           // k per chunk
#define NCH (HIDDEN/BK) // 32 chunks

typedef __attribute__((ext_vector_type(4))) float f32x4;
typedef __attribute__((ext_vector_type(8))) short short8;

__device__ __forceinline__ unsigned cvtpk_bf16(float a, float b) {
    unsigned r;
    asm("v_cvt_pk_bf16_f32 %0, %1, %2" : "=v"(r) : "v"(a), "v"(b));
    return r;
}

// scalar RNE f32->bf16 (convert kernel only; not perf-critical)
__device__ __forceinline__ unsigned short f2bf(float x) {
    union { float f; unsigned u; } v; v.f = x;
    unsigned r = v.u + 0x7FFF + ((v.u >> 16) & 1);
    return (unsigned short)(r >> 16);
}

// ---------------------------------------------------------------------------
// Kernel 0 v2: convert + swizzle W{g,s,v} (fp32 [49][2048]) into MFMA
// B-fragment order, st-contiguous (unchanged, proven):
//   index tau = ((m*64 + st)*4 + c)*64 + lane   (8 bf16 = 16B per entry)
// ---------------------------------------------------------------------------
__global__ __launch_bounds__(256) void convert_w(
    const float* __restrict__ Wg, const float* __restrict__ Ws,
    const float* __restrict__ Wv, unsigned short* __restrict__ Wf)
{
    int tau = blockIdx.x * 256 + threadIdx.x;      // 0..49151
    int m   = tau >> 14;
    int rem = tau & 16383;
    int st  = rem >> 8;
    int c   = (rem >> 6) & 3;
    int l   = rem & 63;
    int col = c * 16 + (l & 15);
    int k0  = st * 32 + ((l >> 4) << 3);

    const float* W = (m == 0) ? Wg : (m == 1) ? Ws : Wv;
    unsigned short out[8];
    if (col < NK) {
        const float* p = W + (size_t)col * HIDDEN + k0;
        #pragma unroll
        for (int j = 0; j < 8; j++) out[j] = f2bf(p[j]);
    } else {
        #pragma unroll
        for (int j = 0; j < 8; j++) out[j] = 0;
    }
    unsigned short* dst = Wf + (size_t)tau * 8;
    #pragma unroll
    for (int j = 0; j < 8; j++) dst[j] = out[j];
}

// ---------------------------------------------------------------------------
// Kernel 1 v7 (m97 structure): 128-row block, BK=64 chunks, both operands
// staged in LDS via global_load_lds DMA, double-buffered, one barrier/chunk.
// A: one DMA instr = 4 rows x 256B contiguous (vs 16 scattered 16B segs in
// v2-v6 — the shared flaw). Source-side XOR swizzle (slot^(row&7)), linear
// LDS dest, swizzled ds_read -> 2 lanes/bank (free). B: proven DMA path.
// Barrier placed BEFORE next-chunk issue: drain covers only chunk ch;
// DMA(ch+1) overlaps compute(ch). Math bit-identical to R2 (absmax 0.0156).
// ---------------------------------------------------------------------------
__global__ __launch_bounds__(512) void gemm_mfma(
    const float* __restrict__ h, const float* __restrict__ s,
    const float* __restrict__ V, const unsigned short* __restrict__ Wf,
    float* __restrict__ pg, float* __restrict__ ps, float* __restrict__ pv)
{
    int tid = threadIdx.x;
    int w = tid >> 6, lane = tid & 63;
    int blk = blockIdx.x;

    const float* A; float* C; int rowBase; const unsigned short* wfm; int Mrows;
    if (blk < 256)      { A = h; C = pg; rowBase = blk * BM;         wfm = Wf;                       Mrows = 32768; }
    else if (blk < 512) { A = s; C = ps; rowBase = (blk - 256) * BM; wfm = Wf + (size_t)16384 * 8;   Mrows = 32768; }
    else                { A = V; C = pv; rowBase = (blk - 512) * BM; wfm = Wf + (size_t)32768 * 8;   Mrows = 3136;  }

    __shared__ float  Alds[2][BM * BK];   // 2 x 32 KB, fp32, row stride 64
    __shared__ short8 Blds[2][512];       // 2 x 8 KB: [st][c][lane]

    const short8* wfp = (const short8*)wfm;
    int rt0 = w * 16;                     // wave's first tile row

    f32x4 acc0 = {0.f, 0.f, 0.f, 0.f};
    f32x4 acc1 = acc0, acc2 = acc0, acc3 = acc0;

    // --- DMA one chunk (A: 4 instr/wave = 16 rows; B: 1 instr/wave) ---
#define DMA_AB(ch, buf) { \
    _Pragma("unroll") \
    for (int i = 0; i < 4; i++) { \
        int rt = rt0 + i * 4 + (lane >> 4); \
        int gr = rowBase + rt; if (gr > Mrows - 1) gr = Mrows - 1; \
        int sg = (lane & 15) ^ (rt & 7); \
        const float* src = A + (size_t)gr * HIDDEN + (ch) * BK + sg * 4; \
        __builtin_amdgcn_global_load_lds((const void*)src, \
            (void*)&Alds[buf][(rt0 + i * 4) * BK], 16, 0, 0); \
    } \
    { const short8* srcb = wfp + (size_t)((ch) * 8 + w) * 64 + lane; \
      __builtin_amdgcn_global_load_lds((const void*)srcb, \
          (void*)&Blds[buf][w * 64], 16, 0, 0); } }

    // --- consume one chunk: 2 st x (2 A ds_reads + 4 B ds_reads + 4 MFMA) ---
#define CHUNK_COMPUTE(buf) { \
    const float*  al = &Alds[buf][0]; \
    const short8* bl = &Blds[buf][0]; \
    int rr = lane & 15; \
    int row = rt0 + rr; \
    _Pragma("unroll") \
    for (int st = 0; st < 2; st++) { \
        int cs = st * 8 + ((lane >> 4) << 1); \
        float4 f0 = *(const float4*)&al[row * BK + ((cs    ) ^ (rr & 7)) * 4]; \
        float4 f1 = *(const float4*)&al[row * BK + ((cs + 1) ^ (rr & 7)) * 4]; \
        union { short8 v; unsigned u[4]; } a_; \
        a_.u[0] = cvtpk_bf16(f0.x, f0.y); \
        a_.u[1] = cvtpk_bf16(f0.z, f0.w); \
        a_.u[2] = cvtpk_bf16(f1.x, f1.y); \
        a_.u[3] = cvtpk_bf16(f1.z, f1.w); \
        short8 b0 = bl[(st * 4 + 0) * 64 + lane]; \
        short8 b1 = bl[(st * 4 + 1) * 64 + lane]; \
        short8 b2 = bl[(st * 4 + 2) * 64 + lane]; \
        short8 b3 = bl[(st * 4 + 3) * 64 + lane]; \
        acc0 = __builtin_amdgcn_mfma_f32_16x16x32_bf16(a_.v, b0, acc0, 0, 0, 0); \
        acc1 = __builtin_amdgcn_mfma_f32_16x16x32_bf16(a_.v, b1, acc1, 0, 0, 0); \
        acc2 = __builtin_amdgcn_mfma_f32_16x16x32_bf16(a_.v, b2, acc2, 0, 0, 0); \
        acc3 = __builtin_amdgcn_mfma_f32_16x16x32_bf16(a_.v, b3, acc3, 0, 0, 0); \
    } }

    DMA_AB(0, 0)

    #pragma unroll 1
    for (int ch = 0; ch < NCH; ch++) {
        int cur = ch & 1;
        __syncthreads();                     // drains DMA(ch); orders nxt reuse
        if (ch + 1 < NCH) { DMA_AB(ch + 1, cur ^ 1) }  // flies over compute
        CHUNK_COMPUTE(cur)
    }

#undef DMA_AB
#undef CHUNK_COMPUTE

    // C/D layout (verified m89): col = lane&15, row = (lane>>4)*4 + reg
    int colb  = lane & 15;
    int rquad = (lane >> 4) << 2;
    int rowb  = rowBase + rt0 + rquad;
    float* crow = C + (size_t)rowb * NK + colb;
    #pragma unroll
    for (int r = 0; r < 4; r++) {
        if (rowb + r < Mrows) {
            crow[(size_t)r * NK + 0]  = acc0[r];
            crow[(size_t)r * NK + 16] = acc1[r];
            crow[(size_t)r * NK + 32] = acc2[r];
            if (colb == 0) crow[(size_t)r * NK + 48] = acc3[r];
        }
    }
}

// fast tanh: 1 - 2/(exp(2x)+1); safe at +-inf of exp
__device__ __forceinline__ float ftanh(float x) {
    float e = __expf(2.f * x);
    return 1.f - 2.f * __builtin_amdgcn_rcpf(e + 1.f);
}

// ---------------------------------------------------------------------------
// Kernel 2: per-(b,t) scores + softmaxes. One wave per row (b,t). (unchanged)
// ---------------------------------------------------------------------------
__global__ __launch_bounds__(256) void zab_kernel(
    const float* __restrict__ pg, const float* __restrict__ ps,
    const float* __restrict__ pv, const float* __restrict__ Wh,
    float* __restrict__ alpha, float* __restrict__ beta)
{
    int w = threadIdx.x >> 6, lane = threadIdx.x & 63;
    int row = blockIdx.x * 4 + w;        // 0..32767
    int b = row >> 9;

    const float* pgrow = pg + (size_t)row * NK;
    const float* psrow = ps + (size_t)row * NK;

    // phase A: z_ext
    float va = 0.f;
    if (lane < NK)
        va = ftanh(psrow[lane] + pgrow[lane]) * Wh[lane];
    float z_ext = va;
    #pragma unroll
    for (int off = 32; off; off >>= 1) z_ext += __shfl_xor(z_ext, off);

    // phase B: z[k]
    float z = -1e30f;
    if (lane < NK) {
        const float* pvrow = pv + ((size_t)b * NK + lane) * NK;
        float acc = 0.f;
        for (int j = 0; j < NK; j++)
            acc = fmaf(ftanh(pvrow[j] + pgrow[j]), Wh[j], acc);
        z = acc;
    }

    // softmax over k (49)
    float m = z;
    #pragma unroll
    for (int off = 32; off; off >>= 1) m = fmaxf(m, __shfl_xor(m, off));
    float p = (lane < NK) ? __expf(z - m) : 0.f;
    float ssum = p;
    #pragma unroll
    for (int off = 32; off; off >>= 1) ssum += __shfl_xor(ssum, off);
    float a = p * __builtin_amdgcn_rcpf(ssum);

    if (lane < NK)
        alpha[(size_t)row * NK + lane] = a;

    // extended softmax -> beta
    float me = fmaxf(m, z_ext);
    float se = ssum * __expf(m - me) + __expf(z_ext - me);
    float bet = __expf(z_ext - me) * __builtin_amdgcn_rcpf(se);
    if (lane == 0) beta[row] = bet;
}

// ---------------------------------------------------------------------------
// Kernel 3: c_hat = beta*sent + (1-beta)*(alpha @ V). (unchanged)
// ---------------------------------------------------------------------------
__global__ __launch_bounds__(256) void chat_kernel(
    const float* __restrict__ V, const float* __restrict__ sent,
    const float* __restrict__ alpha, const float* __restrict__ beta,
    float* __restrict__ chat)
{
    int d0 = blockIdx.x * 128;
    int t0 = blockIdx.y * 32;
    int b  = blockIdx.z;

    __shared__ float alpha_s[NK][36];   // transposed: [k][t], stride 36
    __shared__ float beta_s[32];

    int tid = threadIdx.x;

    const float* arow = alpha + ((size_t)b * NT + t0) * NK;  // 1568 contiguous
    for (int i = tid; i < 32 * NK; i += 256) {
        int t = i / NK, k = i - t * NK;
        alpha_s[k][t] = arow[i];
    }
    if (tid < 32) beta_s[tid] = beta[(size_t)b * NT + t0 + tid];
    __syncthreads();

    int tx = tid & 31;          // d-group: d = d0 + tx*4
    int ty = tid >> 5;          // t-group: t = t0 + ty*4 + i

    const float* vp = V + (size_t)b * NK * HIDDEN + d0 + tx * 4;

    float4 acc[4];
    #pragma unroll
    for (int i = 0; i < 4; i++) acc[i] = make_float4(0.f, 0.f, 0.f, 0.f);

    #pragma unroll 7
    for (int k = 0; k < NK; k++) {
        float4 vv = *(const float4*)(vp + (size_t)k * HIDDEN);
        float4 a4 = *(const float4*)&alpha_s[k][ty * 4];
        acc[0].x = fmaf(a4.x, vv.x, acc[0].x);
        acc[0].y = fmaf(a4.x, vv.y, acc[0].y);
        acc[0].z = fmaf(a4.x, vv.z, acc[0].z);
        acc[0].w = fmaf(a4.x, vv.w, acc[0].w);
        acc[1].x = fmaf(a4.y, vv.x, acc[1].x);
        acc[1].y = fmaf(a4.y, vv.y, acc[1].y);
        acc[1].z = fmaf(a4.y, vv.z, acc[1].z);
        acc[1].w = fmaf(a4.y, vv.w, acc[1].w);
        acc[2].x = fmaf(a4.z, vv.x, acc[2].x);
        acc[2].y = fmaf(a4.z, vv.y, acc[2].y);
        acc[2].z = fmaf(a4.z, vv.z, acc[2].z);
        acc[2].w = fmaf(a4.z, vv.w, acc[2].w);
        acc[3].x = fmaf(a4.w, vv.x, acc[3].x);
        acc[3].y = fmaf(a4.w, vv.y, acc[3].y);
        acc[3].z = fmaf(a4.w, vv.z, acc[3].z);
        acc[3].w = fmaf(a4.w, vv.w, acc[3].w);
    }

    #pragma unroll
    for (int i = 0; i < 4; i++) {
        int t = ty * 4 + i;
        float bt = beta_s[t];
        const float* sp = sent + ((size_t)b * NT + t0 + t) * HIDDEN + d0 + tx * 4;
        float*       op = chat + ((size_t)b * NT + t0 + t) * HIDDEN + d0 + tx * 4;
        float4 sv = *(const float4*)sp;
        float4 o;
        o.x = fmaf(bt, sv.x, (1.f - bt) * acc[i].x);
        o.y = fmaf(bt, sv.y, (1.f - bt) * acc[i].y);
        o.z = fmaf(bt, sv.z, (1.f - bt) * acc[i].z);
        o.w = fmaf(bt, sv.w, (1.f - bt) * acc[i].w);
        *(float4*)op = o;
    }
}

extern "C" void kernel_launch(void* const* d_in, const int* in_sizes, int n_in,
                              void* d_out, int out_size, void* d_ws, size_t ws_size,
                              hipStream_t stream)
{
    const float* V    = (const float*)d_in[0];
    const float* h_t  = (const float*)d_in[1];
    const float* sent = (const float*)d_in[2];
    const float* Wv   = (const float*)d_in[3];
    const float* Wg   = (const float*)d_in[4];
    const float* Ws   = (const float*)d_in[5];
    const float* Wh   = (const float*)d_in[6];

    float* out   = (float*)d_out;
    float* chat  = out;                                   // B*T*HIDDEN
    float* alpha = out + (size_t)NB * NT * HIDDEN;        // B*T*K
    float* beta  = alpha + (size_t)NB * NT * NK;          // B*T

    float* ws = (float*)d_ws;
    float* pg = ws;                                       // 32768*49
    float* ps = pg + (size_t)NB * NT * NK;                // 32768*49
    float* pv = ps + (size_t)NB * NT * NK;                // 3136*49
    unsigned short* Wf = (unsigned short*)(pv + (size_t)NB * NK * NK); // 3*16384*8 bf16

    convert_w<<<192, 256, 0, stream>>>(Wg, Ws, Wv, Wf);
    // 256 (pg) + 256 (ps) + 25 (pv, last block row-masked) blocks
    gemm_mfma<<<537, 512, 0, stream>>>(h_t, sent, V, Wf, pg, ps, pv);
    zab_kernel<<<(NB * NT) / 4, 256, 0, stream>>>(pg, ps, pv, Wh, alpha, beta);
    chat_kernel<<<dim3(HIDDEN / 128, NT / 32, NB), 256, 0, stream>>>(V, sent, alpha, beta, chat);
}